// Round 5
// baseline (242.395 us; speedup 1.0000x reference)
//
#include <hip/hip_runtime.h>
#include <stdint.h>

// WaveletLayer fused kernel (fp32): db2 DWT (symmetric ext) -> scale cD by
// weight[0] -> db2 IDWT -> leaky_relu(0.01).
//
// R6 structure: one WAVE = EIGHT rows of N=512, FLAT (no loop). Lane t owns
// 8 consecutive floats of each row; all 16 dwordx4 loads are issued before
// any use -> 256 B/lane in flight, and there is no loop-boundary register
// reuse forcing a store->load serialization (R5 had only 2 grid-stride
// iterations per wave and stalled at ~3.8 TB/s effective).
// Cache policy split (R5 post-mortem):
//   LOADS are CACHED  — R3 profile showed FETCH_SIZE=65 MB for a 128 MiB
//     input: ~half of x is L3-resident across iterations; NT loads forfeit
//     those free hits (R5's mistake).
//   STORES are NONTEMPORAL — out is never re-read; not allocating it in L3
//     (a) leaves room for x to stay resident, (b) avoids dirty-line
//     writeback interference. The 6.7 TB/s plain-store fill (FETCH=14.5 KB,
//     no RFO) bounds the store drain path; NT uses the same path without
//     allocation.
// Halo (2 floats each side) via 4 __shfl per row; no LDS, no barrier.
// Per-lane weights in registers (cached loads, reused).
//
// Index algebra (harness-verified R2-R5):
//   cA[i] = DL3*x[2i-2] + DL2*x[2i-1] + DL1*x[2i] + DL0*x[2i+1]  (interior)
//   i=0: taps (x1,x0,x0,x1)   i=256: taps (x510,x511,x511,x510)
//   even j: z = RL2*A[i] + RL0*A[i+1] + RH2*D[i] + RH0*D[i+1],  i=j/2
//   odd  j: z = RL3*A[i] + RL1*A[i+1] + RH3*D[i] + RH1*D[i+1]
//   with D = weight[0] * cD.
// Lane t computes pairs i = 4t..4t+4 and outputs j = 8t..8t+7 of each row.
// Boundary reflections collapse to own-register substitutions at lane 0/63.

#define N 512

typedef float f4v __attribute__((ext_vector_type(4)));

__device__ __forceinline__ void row_compute(
    const f4v va, const f4v vb,
    const float xl0, const float xl1, const float xr0, const float xr1,
    const f4v wv, const float w4,
    f4v& oa, f4v& ob)
{
    constexpr float DL0 = -0.12940952255092145f, DL1 = 0.22414386804185735f,
                    DL2 =  0.836516303737469f,   DL3 = 0.48296291314469025f;
    constexpr float DH0 = -0.48296291314469025f, DH1 = 0.836516303737469f,
                    DH2 = -0.22414386804185735f, DH3 = -0.12940952255092145f;
    constexpr float RL0 =  0.48296291314469025f, RL1 = 0.836516303737469f,
                    RL2 =  0.22414386804185735f, RL3 = -0.12940952255092145f;
    constexpr float RH0 = -0.12940952255092145f, RH1 = -0.22414386804185735f,
                    RH2 =  0.836516303737469f,   RH3 = -0.48296291314469025f;

    float A0 = DL3*xl0  + DL2*xl1  + DL1*va.x + DL0*va.y;
    float D0 = DH3*xl0  + DH2*xl1  + DH1*va.x + DH0*va.y;
    float A1 = DL3*va.x + DL2*va.y + DL1*va.z + DL0*va.w;
    float D1 = DH3*va.x + DH2*va.y + DH1*va.z + DH0*va.w;
    float A2 = DL3*va.z + DL2*va.w + DL1*vb.x + DL0*vb.y;
    float D2 = DH3*va.z + DH2*va.w + DH1*vb.x + DH0*vb.y;
    float A3 = DL3*vb.x + DL2*vb.y + DL1*vb.z + DL0*vb.w;
    float D3 = DH3*vb.x + DH2*vb.y + DH1*vb.z + DH0*vb.w;
    float A4 = DL3*vb.z + DL2*vb.w + DL1*xr0  + DL0*xr1;
    float D4 = DH3*vb.z + DH2*vb.w + DH1*xr0  + DH0*xr1;

    D0 *= wv.x; D1 *= wv.y; D2 *= wv.z; D3 *= wv.w; D4 *= w4;

    float z0 = RL2*A0 + RL0*A1 + RH2*D0 + RH0*D1;
    float z1 = RL3*A0 + RL1*A1 + RH3*D0 + RH1*D1;
    float z2 = RL2*A1 + RL0*A2 + RH2*D1 + RH0*D2;
    float z3 = RL3*A1 + RL1*A2 + RH3*D1 + RH1*D2;
    float z4 = RL2*A2 + RL0*A3 + RH2*D2 + RH0*D3;
    float z5 = RL3*A2 + RL1*A3 + RH3*D2 + RH1*D3;
    float z6 = RL2*A3 + RL0*A4 + RH2*D3 + RH0*D4;
    float z7 = RL3*A3 + RL1*A4 + RH3*D3 + RH1*D4;

    oa.x = fmaxf(z0, 0.f) + 0.01f * fminf(z0, 0.f);
    oa.y = fmaxf(z1, 0.f) + 0.01f * fminf(z1, 0.f);
    oa.z = fmaxf(z2, 0.f) + 0.01f * fminf(z2, 0.f);
    oa.w = fmaxf(z3, 0.f) + 0.01f * fminf(z3, 0.f);
    ob.x = fmaxf(z4, 0.f) + 0.01f * fminf(z4, 0.f);
    ob.y = fmaxf(z5, 0.f) + 0.01f * fminf(z5, 0.f);
    ob.z = fmaxf(z6, 0.f) + 0.01f * fminf(z6, 0.f);
    ob.w = fmaxf(z7, 0.f) + 0.01f * fminf(z7, 0.f);
}

__device__ __forceinline__ void halo(
    const f4v va, const f4v vb, const int lane,
    float& xl0, float& xl1, float& xr0, float& xr1)
{
    xl0 = __shfl_up(vb.z, 1);
    xl1 = __shfl_up(vb.w, 1);
    xr0 = __shfl_down(va.x, 1);
    xr1 = __shfl_down(va.y, 1);
    if (lane == 0)  { xl0 = va.y; xl1 = va.x; }
    if (lane == 63) { xr0 = vb.w; xr1 = vb.z; }
}

// one row: halo + compute + NT store
#define DO_ROW(VA, VB, BASE)                                            \
    do {                                                                \
        float xl0, xl1, xr0, xr1;                                       \
        f4v oa, ob;                                                     \
        halo(VA, VB, lane, xl0, xl1, xr0, xr1);                         \
        row_compute(VA, VB, xl0, xl1, xr0, xr1, wv, w4, oa, ob);        \
        __builtin_nontemporal_store(oa, (f4v*)(out + (BASE)));          \
        __builtin_nontemporal_store(ob, (f4v*)(out + (BASE) + 4));      \
    } while (0)

__global__ __launch_bounds__(256) void wavelet_kernel(
    const float* __restrict__ x,
    const float* __restrict__ w,
    float* __restrict__ out,
    int nrows)
{
    const int lane = threadIdx.x & 63;
    const int wid  = threadIdx.x >> 6;

    // Per-lane weights: lane t scales pairs i = 4t .. 4t+4.
    const f4v  wv = *(const f4v*)(w + 4 * lane);
    const float w4 = w[4 * lane + 4];

    const int octet = (int)blockIdx.x * 4 + wid;   // 8 rows per wave, flat
    const int r0 = octet * 8;
    if (r0 >= nrows) return;

    const size_t base0 = (size_t)r0 * N + ((size_t)lane << 3);

    if (r0 + 8 <= nrows) {
        // issue all 16 cached loads before any use: 256 B/lane in flight
        f4v va0 = *(const f4v*)(x + base0);
        f4v vb0 = *(const f4v*)(x + base0 + 4);
        f4v va1 = *(const f4v*)(x + base0 + 1 * N);
        f4v vb1 = *(const f4v*)(x + base0 + 1 * N + 4);
        f4v va2 = *(const f4v*)(x + base0 + 2 * N);
        f4v vb2 = *(const f4v*)(x + base0 + 2 * N + 4);
        f4v va3 = *(const f4v*)(x + base0 + 3 * N);
        f4v vb3 = *(const f4v*)(x + base0 + 3 * N + 4);
        f4v va4 = *(const f4v*)(x + base0 + 4 * N);
        f4v vb4 = *(const f4v*)(x + base0 + 4 * N + 4);
        f4v va5 = *(const f4v*)(x + base0 + 5 * N);
        f4v vb5 = *(const f4v*)(x + base0 + 5 * N + 4);
        f4v va6 = *(const f4v*)(x + base0 + 6 * N);
        f4v vb6 = *(const f4v*)(x + base0 + 6 * N + 4);
        f4v va7 = *(const f4v*)(x + base0 + 7 * N);
        f4v vb7 = *(const f4v*)(x + base0 + 7 * N + 4);

        DO_ROW(va0, vb0, base0);
        DO_ROW(va1, vb1, base0 + 1 * N);
        DO_ROW(va2, vb2, base0 + 2 * N);
        DO_ROW(va3, vb3, base0 + 3 * N);
        DO_ROW(va4, vb4, base0 + 4 * N);
        DO_ROW(va5, vb5, base0 + 5 * N);
        DO_ROW(va6, vb6, base0 + 6 * N);
        DO_ROW(va7, vb7, base0 + 7 * N);
    } else {
        // tail (not hit for B=65536, kept for generality)
        for (int r = r0; r < nrows; ++r) {
            const size_t b = (size_t)r * N + ((size_t)lane << 3);
            f4v va = *(const f4v*)(x + b);
            f4v vb = *(const f4v*)(x + b + 4);
            DO_ROW(va, vb, b);
        }
    }
}

extern "C" void kernel_launch(void* const* d_in, const int* in_sizes, int n_in,
                              void* d_out, int out_size, void* d_ws, size_t ws_size,
                              hipStream_t stream) {
    const float* x = (const float*)d_in[0];
    const float* w = (const float*)d_in[1];
    float* out = (float*)d_out;

    const int nrows = in_sizes[0] / N;           // element count / row length
    const int octets = (nrows + 7) / 8;
    int blocks = (octets + 3) / 4;               // 4 waves (octets) per block
    if (blocks < 1) blocks = 1;
    wavelet_kernel<<<blocks, 256, 0, stream>>>(x, w, out, nrows);
}

// Round 6
// 233.675 us; speedup vs baseline: 1.0373x; 1.0373x over previous
//
#include <hip/hip_runtime.h>
#include <stdint.h>

// WaveletLayer fused kernel (fp32): db2 DWT (symmetric ext) -> scale cD by
// weight[0] -> db2 IDWT -> leaky_relu(0.01).
//
// R7 structure: one WAVE = 16 contiguous rows of N=512, processed as FOUR
// 4-row batches with SOFTWARE DOUBLE-BUFFERING: issue batch k+1's 8 dwordx4
// loads, sched_barrier(0), then compute+store batch k. R6 showed the
// compiler will NOT hold a flat 16-load batch (it chose VGPR=48 and
// re-serialized, ~130 B/wave actually in flight, 2.9 TB/s). The explicit
// 2-deep pipeline + sched_barrier(0) (which forbids sinking the prefetch
// below the compute) keeps 8 loads (128 B/lane) continuously in flight with
// only 16 f4v of live data (~90 VGPR, ~5 waves/SIMD).
//
// Cache policy (from the R3-R6 2x2):
//   cached+NT   = 85/91 us (R3,R6)   plain+cached = ~73 (R4)   NT+NT = ~70 (R5)
//   LOADS CACHED: L3 serves ~65 MB/iter free (FETCH=65 MB measured); L2
//     dedupes the stride-32B interleaved va/vb halves (NT loads can't -> up
//     to 2x fetch).
//   STORES PLAIN: ack at L2 (~100-200 cy) instead of HBM, staying off the
//     vmcnt critical chain; the 6.7 TB/s fill proves this path's rate.
//     vmcnt retires oldest-first, so load-waits never wait on younger stores.
//
// Halo (2 floats each side) via 4 __shfl per row; no LDS, no barrier.
// Per-lane weights in registers (lane t scales pairs i = 4t..4t+4).
//
// Index algebra (harness-verified R2-R6):
//   cA[i] = DL3*x[2i-2] + DL2*x[2i-1] + DL1*x[2i] + DL0*x[2i+1]  (interior)
//   i=0: taps (x1,x0,x0,x1)   i=256: taps (x510,x511,x511,x510)
//   even j: z = RL2*A[i] + RL0*A[i+1] + RH2*D[i] + RH0*D[i+1],  i=j/2
//   odd  j: z = RL3*A[i] + RL1*A[i+1] + RH3*D[i] + RH1*D[i+1]
//   with D = weight[0] * cD.
// Lane t computes pairs i = 4t..4t+4 and outputs j = 8t..8t+7 of each row.
// Boundary reflections collapse to own-register substitutions at lane 0/63.

#define N 512

typedef float f4v __attribute__((ext_vector_type(4)));

__device__ __forceinline__ void row_compute(
    const f4v va, const f4v vb,
    const float xl0, const float xl1, const float xr0, const float xr1,
    const f4v wv, const float w4,
    f4v& oa, f4v& ob)
{
    constexpr float DL0 = -0.12940952255092145f, DL1 = 0.22414386804185735f,
                    DL2 =  0.836516303737469f,   DL3 = 0.48296291314469025f;
    constexpr float DH0 = -0.48296291314469025f, DH1 = 0.836516303737469f,
                    DH2 = -0.22414386804185735f, DH3 = -0.12940952255092145f;
    constexpr float RL0 =  0.48296291314469025f, RL1 = 0.836516303737469f,
                    RL2 =  0.22414386804185735f, RL3 = -0.12940952255092145f;
    constexpr float RH0 = -0.12940952255092145f, RH1 = -0.22414386804185735f,
                    RH2 =  0.836516303737469f,   RH3 = -0.48296291314469025f;

    float A0 = DL3*xl0  + DL2*xl1  + DL1*va.x + DL0*va.y;
    float D0 = DH3*xl0  + DH2*xl1  + DH1*va.x + DH0*va.y;
    float A1 = DL3*va.x + DL2*va.y + DL1*va.z + DL0*va.w;
    float D1 = DH3*va.x + DH2*va.y + DH1*va.z + DH0*va.w;
    float A2 = DL3*va.z + DL2*va.w + DL1*vb.x + DL0*vb.y;
    float D2 = DH3*va.z + DH2*va.w + DH1*vb.x + DH0*vb.y;
    float A3 = DL3*vb.x + DL2*vb.y + DL1*vb.z + DL0*vb.w;
    float D3 = DH3*vb.x + DH2*vb.y + DH1*vb.z + DH0*vb.w;
    float A4 = DL3*vb.z + DL2*vb.w + DL1*xr0  + DL0*xr1;
    float D4 = DH3*vb.z + DH2*vb.w + DH1*xr0  + DH0*xr1;

    D0 *= wv.x; D1 *= wv.y; D2 *= wv.z; D3 *= wv.w; D4 *= w4;

    float z0 = RL2*A0 + RL0*A1 + RH2*D0 + RH0*D1;
    float z1 = RL3*A0 + RL1*A1 + RH3*D0 + RH1*D1;
    float z2 = RL2*A1 + RL0*A2 + RH2*D1 + RH0*D2;
    float z3 = RL3*A1 + RL1*A2 + RH3*D1 + RH1*D2;
    float z4 = RL2*A2 + RL0*A3 + RH2*D2 + RH0*D3;
    float z5 = RL3*A2 + RL1*A3 + RH3*D2 + RH1*D3;
    float z6 = RL2*A3 + RL0*A4 + RH2*D3 + RH0*D4;
    float z7 = RL3*A3 + RL1*A4 + RH3*D3 + RH1*D4;

    oa.x = fmaxf(z0, 0.f) + 0.01f * fminf(z0, 0.f);
    oa.y = fmaxf(z1, 0.f) + 0.01f * fminf(z1, 0.f);
    oa.z = fmaxf(z2, 0.f) + 0.01f * fminf(z2, 0.f);
    oa.w = fmaxf(z3, 0.f) + 0.01f * fminf(z3, 0.f);
    ob.x = fmaxf(z4, 0.f) + 0.01f * fminf(z4, 0.f);
    ob.y = fmaxf(z5, 0.f) + 0.01f * fminf(z5, 0.f);
    ob.z = fmaxf(z6, 0.f) + 0.01f * fminf(z6, 0.f);
    ob.w = fmaxf(z7, 0.f) + 0.01f * fminf(z7, 0.f);
}

__device__ __forceinline__ void halo(
    const f4v va, const f4v vb, const int lane,
    float& xl0, float& xl1, float& xr0, float& xr1)
{
    xl0 = __shfl_up(vb.z, 1);
    xl1 = __shfl_up(vb.w, 1);
    xr0 = __shfl_down(va.x, 1);
    xr1 = __shfl_down(va.y, 1);
    if (lane == 0)  { xl0 = va.y; xl1 = va.x; }
    if (lane == 63) { xr0 = vb.w; xr1 = vb.z; }
}

// one row: halo + compute + PLAIN store
#define DO_ROW(VA, VB, BASE)                                            \
    do {                                                                \
        float xl0, xl1, xr0, xr1;                                       \
        f4v oa, ob;                                                     \
        halo(VA, VB, lane, xl0, xl1, xr0, xr1);                         \
        row_compute(VA, VB, xl0, xl1, xr0, xr1, wv, w4, oa, ob);        \
        *(f4v*)(out + (BASE))     = oa;                                 \
        *(f4v*)(out + (BASE) + 4) = ob;                                 \
    } while (0)

// issue the 8 loads of the batch at NB into the n-registers, then fence the
// schedule so they cannot sink below the following compute
#define PREFETCH(NB)                                                    \
    do {                                                                \
        na0 = *(const f4v*)(x + (NB));                                  \
        nb0 = *(const f4v*)(x + (NB) + 4);                              \
        na1 = *(const f4v*)(x + (NB) + 1 * N);                          \
        nb1 = *(const f4v*)(x + (NB) + 1 * N + 4);                      \
        na2 = *(const f4v*)(x + (NB) + 2 * N);                          \
        nb2 = *(const f4v*)(x + (NB) + 2 * N + 4);                      \
        na3 = *(const f4v*)(x + (NB) + 3 * N);                          \
        nb3 = *(const f4v*)(x + (NB) + 3 * N + 4);                      \
        __builtin_amdgcn_sched_barrier(0);                              \
    } while (0)

#define COMPUTE_CUR()                                                   \
    do {                                                                \
        DO_ROW(ca0, cb0, base);                                         \
        DO_ROW(ca1, cb1, base + 1 * N);                                 \
        DO_ROW(ca2, cb2, base + 2 * N);                                 \
        DO_ROW(ca3, cb3, base + 3 * N);                                 \
    } while (0)

#define ROTATE(NB)                                                      \
    do {                                                                \
        ca0 = na0; cb0 = nb0; ca1 = na1; cb1 = nb1;                     \
        ca2 = na2; cb2 = nb2; ca3 = na3; cb3 = nb3;                     \
        base = (NB);                                                    \
    } while (0)

__global__ __launch_bounds__(256) void wavelet_kernel(
    const float* __restrict__ x,
    const float* __restrict__ w,
    float* __restrict__ out,
    int nrows)
{
    const int lane = threadIdx.x & 63;
    const int wid  = threadIdx.x >> 6;

    const f4v  wv = *(const f4v*)(w + 4 * lane);
    const float w4 = w[4 * lane + 4];

    const int wave_id = (int)blockIdx.x * 4 + wid;   // 16 rows per wave
    const int r0 = wave_id * 16;
    if (r0 >= nrows) return;

    size_t base = (size_t)r0 * N + ((size_t)lane << 3);

    if (r0 + 16 <= nrows) {
        // batch 0 prefetch (8 cached loads), fenced
        f4v ca0 = *(const f4v*)(x + base);
        f4v cb0 = *(const f4v*)(x + base + 4);
        f4v ca1 = *(const f4v*)(x + base + 1 * N);
        f4v cb1 = *(const f4v*)(x + base + 1 * N + 4);
        f4v ca2 = *(const f4v*)(x + base + 2 * N);
        f4v cb2 = *(const f4v*)(x + base + 2 * N + 4);
        f4v ca3 = *(const f4v*)(x + base + 3 * N);
        f4v cb3 = *(const f4v*)(x + base + 3 * N + 4);
        __builtin_amdgcn_sched_barrier(0);

        f4v na0, nb0, na1, nb1, na2, nb2, na3, nb3;

        // stage 1: prefetch rows 4-7, compute rows 0-3
        PREFETCH(base + 4 * N);
        COMPUTE_CUR();
        ROTATE(base + 4 * N);

        // stage 2: prefetch rows 8-11, compute rows 4-7
        PREFETCH(base + 4 * N);
        COMPUTE_CUR();
        ROTATE(base + 4 * N);

        // stage 3: prefetch rows 12-15, compute rows 8-11
        PREFETCH(base + 4 * N);
        COMPUTE_CUR();
        ROTATE(base + 4 * N);

        // stage 4: drain — compute rows 12-15
        COMPUTE_CUR();
    } else {
        // tail (not hit for B=65536, kept for generality)
        for (int r = r0; r < nrows; ++r) {
            const size_t b = (size_t)r * N + ((size_t)lane << 3);
            f4v va = *(const f4v*)(x + b);
            f4v vb = *(const f4v*)(x + b + 4);
            float xl0, xl1, xr0, xr1;
            f4v oa, ob;
            halo(va, vb, lane, xl0, xl1, xr0, xr1);
            row_compute(va, vb, xl0, xl1, xr0, xr1, wv, w4, oa, ob);
            *(f4v*)(out + b)     = oa;
            *(f4v*)(out + b + 4) = ob;
        }
    }
}

extern "C" void kernel_launch(void* const* d_in, const int* in_sizes, int n_in,
                              void* d_out, int out_size, void* d_ws, size_t ws_size,
                              hipStream_t stream) {
    const float* x = (const float*)d_in[0];
    const float* w = (const float*)d_in[1];
    float* out = (float*)d_out;

    const int nrows = in_sizes[0] / N;            // element count / row length
    const int waves = (nrows + 15) / 16;          // 16 rows per wave
    int blocks = (waves + 3) / 4;                 // 4 waves per block
    if (blocks < 1) blocks = 1;
    wavelet_kernel<<<blocks, 256, 0, stream>>>(x, w, out, nrows);
}